// Round 1
// baseline (429.660 us; speedup 1.0000x reference)
//
#include <hip/hip_runtime.h>
#include <hip/hip_bf16.h>

// ---------------------------------------------------------------------------
// DisNet: clf CE + nearest-neighbor distill + multi-kernel MMD
// Structure:
//   K0 init       : zero accumulators, set min-keys to ULLONG_MAX
//   K1 sq         : per-row squared norms (8192 rows)
//   K1b colsum    : feature column sums (for closed-form sum(l2))
//   K2 bw         : bandwidth = (2nS - 2|s|^2)/(n^2-n)/4
//   K3 pair       : tiled pairwise kernel. z=0: xx upper-tri, z=1: yy upper-tri,
//                   z=2: xy full (also row/col argmin via u64 atomicMin keys)
//   K4 loss       : CE + two distill terms using argmin indices
//   K5 finalize   : write 3 outputs
// ---------------------------------------------------------------------------

#define NS 4096
#define D  256
#define C  6
#define TS 64
#define KC 32

__global__ __launch_bounds__(256) void k0_init(double* accD,
                                               unsigned long long* rowkey,
                                               unsigned long long* colkey,
                                               float* colsum) {
    int i = blockIdx.x * 256 + threadIdx.x;
    if (i < NS) rowkey[i] = ~0ULL;
    else if (i < 2 * NS) colkey[i - NS] = ~0ULL;
    if (i < 8) accD[i] = 0.0;
    if (i < D) colsum[i] = 0.f;
}

// one block (64 threads) per row: squared norm
__global__ __launch_bounds__(64) void k1_sq(const float* __restrict__ src,
                                            const float* __restrict__ tgt,
                                            float* __restrict__ sq) {
    int r = blockIdx.x;                  // 0..8191
    const float* row = (r < NS) ? (src + (size_t)r * D) : (tgt + (size_t)(r - NS) * D);
    int l = threadIdx.x;                 // 0..63
    float4 v = *(const float4*)&row[l * 4];
    float s = v.x * v.x + v.y * v.y + v.z * v.z + v.w * v.w;
    #pragma unroll
    for (int off = 32; off; off >>= 1) s += __shfl_down(s, off, 64);
    if (l == 0) sq[r] = s;
}

// 256 blocks x 256 threads: block b handles 32 rows, thread c = column c
__global__ __launch_bounds__(256) void k1b_colsum(const float* __restrict__ src,
                                                  const float* __restrict__ tgt,
                                                  float* __restrict__ colsum) {
    int c = threadIdx.x;
    int b = blockIdx.x;
    float part = 0.f;
    for (int r = 0; r < 32; r++) {
        int row = b * 32 + r;
        const float* M = (row < NS) ? (src + (size_t)row * D) : (tgt + (size_t)(row - NS) * D);
        part += M[c];
    }
    atomicAdd(&colsum[c], part);
}

__global__ __launch_bounds__(256) void k2_bw(const float* __restrict__ sq,
                                             const float* __restrict__ colsum,
                                             float* __restrict__ bwp) {
    __shared__ float red[256];
    __shared__ float red2[256];
    int t = threadIdx.x;
    float s = 0.f;
    for (int r = t; r < 2 * NS; r += 256) s += sq[r];
    float c = colsum[t];
    red[t] = s;
    red2[t] = c * c;
    __syncthreads();
    for (int off = 128; off; off >>= 1) {
        if (t < off) { red[t] += red[t + off]; red2[t] += red2[t + off]; }
        __syncthreads();
    }
    if (t == 0) {
        double n = 2.0 * NS;
        double sum_l2 = 2.0 * n * (double)red[0] - 2.0 * (double)red2[0];
        double b = sum_l2 / (n * n - n) / 4.0;   // / KERNEL_MUL^(KERNEL_NUM//2)
        bwp[0] = (float)b;
    }
}

// The big pairwise kernel.
__global__ __launch_bounds__(256) void k3_pair(const float* __restrict__ src,
                                               const float* __restrict__ tgt,
                                               const float* __restrict__ sq,
                                               const float* __restrict__ bwp,
                                               double* accD,
                                               unsigned long long* rowkey,
                                               unsigned long long* colkey) {
    int z  = blockIdx.z;
    int ti = blockIdx.y, tj = blockIdx.x;
    if (z != 2 && ti > tj) return;       // symmetric blocks: upper triangle only

    const float* A   = (z == 1) ? tgt : src;
    const float* B   = (z == 0) ? src : tgt;
    const float* sqA = (z == 1) ? sq + NS : sq;
    const float* sqB = (z == 0) ? sq : sq + NS;

    __shared__ __align__(16) float As[KC][TS];
    __shared__ __align__(16) float Bs[KC][TS];
    __shared__ float red[256];
    __shared__ unsigned long long rmin[TS], cmin[TS];

    int tid = threadIdx.x;
    int tx = tid & 15, ty = tid >> 4;
    int row0 = ti * TS, col0 = tj * TS;

    float acc[4][4] = {};

    for (int kc = 0; kc < D; kc += KC) {
        #pragma unroll
        for (int l = 0; l < 2; l++) {
            int idx = tid + l * 256;
            int r  = idx >> 3;            // 0..63
            int c4 = (idx & 7) * 4;       // 0,4,...,28
            float4 v = *(const float4*)&A[(size_t)(row0 + r) * D + kc + c4];
            As[c4 + 0][r] = v.x; As[c4 + 1][r] = v.y;
            As[c4 + 2][r] = v.z; As[c4 + 3][r] = v.w;
            float4 w = *(const float4*)&B[(size_t)(col0 + r) * D + kc + c4];
            Bs[c4 + 0][r] = w.x; Bs[c4 + 1][r] = w.y;
            Bs[c4 + 2][r] = w.z; Bs[c4 + 3][r] = w.w;
        }
        __syncthreads();
        #pragma unroll
        for (int k = 0; k < KC; k++) {
            float4 av = *(const float4*)&As[k][ty * 4];
            float4 bv = *(const float4*)&Bs[k][tx * 4];
            float a4[4] = {av.x, av.y, av.z, av.w};
            float b4[4] = {bv.x, bv.y, bv.z, bv.w};
            #pragma unroll
            for (int ii = 0; ii < 4; ii++)
                #pragma unroll
                for (int jj = 0; jj < 4; jj++)
                    acc[ii][jj] += a4[ii] * b4[jj];
        }
        __syncthreads();
    }

    float bw = bwp[0];
    float ninv[5];
    #pragma unroll
    for (int t = 0; t < 5; t++) ninv[t] = -1.0f / (bw * (float)(1 << t));

    float tile_sum = 0.f;
    unsigned long long rkey[4], ckey[4];
    #pragma unroll
    for (int q = 0; q < 4; q++) { rkey[q] = ~0ULL; ckey[q] = ~0ULL; }

    #pragma unroll
    for (int ii = 0; ii < 4; ii++) {
        int gi = row0 + ty * 4 + ii;
        float sa = sqA[gi];
        #pragma unroll
        for (int jj = 0; jj < 4; jj++) {
            int gj = col0 + tx * 4 + jj;
            float l2 = sa + sqB[gj] - 2.0f * acc[ii][jj];
            float kv = __expf(l2 * ninv[0]) + __expf(l2 * ninv[1]) +
                       __expf(l2 * ninv[2]) + __expf(l2 * ninv[3]) +
                       __expf(l2 * ninv[4]);
            if (z == 2) {
                tile_sum += kv;
                float d2c = fmaxf(l2, 0.f);
                unsigned long long bits = (unsigned long long)__float_as_uint(d2c) << 32;
                unsigned long long kr = bits | (unsigned)gj;
                unsigned long long kcol = bits | (unsigned)gi;
                if (kr < rkey[ii]) rkey[ii] = kr;
                if (kcol < ckey[jj]) ckey[jj] = kcol;
            } else {
                // strict upper triangle only (diagonal handled analytically)
                if (ti < tj || gi < gj) tile_sum += kv;
            }
        }
    }

    // block-sum -> one double atomic per block
    red[tid] = tile_sum;
    __syncthreads();
    for (int off = 128; off; off >>= 1) {
        if (tid < off) red[tid] += red[tid + off];
        __syncthreads();
    }
    if (tid == 0) atomicAdd(&accD[z], (double)red[0]);

    if (z == 2) {
        if (tid < TS) { rmin[tid] = ~0ULL; cmin[tid] = ~0ULL; }
        __syncthreads();
        #pragma unroll
        for (int ii = 0; ii < 4; ii++) atomicMin(&rmin[ty * 4 + ii], rkey[ii]);
        #pragma unroll
        for (int jj = 0; jj < 4; jj++) atomicMin(&cmin[tx * 4 + jj], ckey[jj]);
        __syncthreads();
        if (tid < TS) atomicMin(&rowkey[row0 + tid], rmin[tid]);
        else if (tid < 2 * TS) atomicMin(&colkey[col0 + tid - TS], cmin[tid - TS]);
    }
}

__global__ __launch_bounds__(256) void k4_loss(const float* __restrict__ sclf,
                                               const float* __restrict__ tclf,
                                               const int* __restrict__ label,
                                               const unsigned long long* __restrict__ rowkey,
                                               const unsigned long long* __restrict__ colkey,
                                               double* accD) {
    int i = blockIdx.x * 256 + threadIdx.x;   // 0..4095
    float clf = 0.f, dis = 0.f;

    // --- source row i softmax stats ---
    const float* x = sclf + (size_t)i * C;
    float mx = x[0];
    #pragma unroll
    for (int c = 1; c < C; c++) mx = fmaxf(mx, x[c]);
    float sx = 0.f;
    #pragma unroll
    for (int c = 0; c < C; c++) sx += __expf(x[c] - mx);
    float lsex = mx + __logf(sx);
    clf = lsex - x[label[i]];

    // --- dis term 1: teacher = src_clf[i], student = tgt_clf[min_idx[i]] ---
    {
        int j = (int)(rowkey[i] & 0xffffffffULL);
        const float* y = tclf + (size_t)j * C;
        float my = y[0];
        #pragma unroll
        for (int c = 1; c < C; c++) my = fmaxf(my, y[c]);
        float sy = 0.f;
        #pragma unroll
        for (int c = 0; c < C; c++) sy += __expf(y[c] - my);
        float lsey = my + __logf(sy);
        float dot = 0.f;
        #pragma unroll
        for (int c = 0; c < C; c++) dot += __expf(x[c] - mx) * y[c];
        dot /= sx;
        dis += lsey - dot;
    }

    // --- dis term 2: teacher = src_clf[min_idx_t[i]], student = tgt_clf[i] ---
    {
        int it = (int)(colkey[i] & 0xffffffffULL);
        const float* xt = sclf + (size_t)it * C;
        float mt = xt[0];
        #pragma unroll
        for (int c = 1; c < C; c++) mt = fmaxf(mt, xt[c]);
        float st = 0.f;
        #pragma unroll
        for (int c = 0; c < C; c++) st += __expf(xt[c] - mt);
        const float* zz = tclf + (size_t)i * C;
        float mz = zz[0];
        #pragma unroll
        for (int c = 1; c < C; c++) mz = fmaxf(mz, zz[c]);
        float sz = 0.f;
        #pragma unroll
        for (int c = 0; c < C; c++) sz += __expf(zz[c] - mz);
        float lsez = mz + __logf(sz);
        float dot2 = 0.f;
        #pragma unroll
        for (int c = 0; c < C; c++) dot2 += __expf(xt[c] - mt) * zz[c];
        dot2 /= st;
        dis += lsez - dot2;
    }

    // wave reduce, then one atomic per wave
    #pragma unroll
    for (int off = 32; off; off >>= 1) {
        clf += __shfl_down(clf, off, 64);
        dis += __shfl_down(dis, off, 64);
    }
    if ((threadIdx.x & 63) == 0) {
        atomicAdd(&accD[3], (double)clf);
        atomicAdd(&accD[4], (double)dis);
    }
}

__global__ void k5_final(const double* __restrict__ accD, float* __restrict__ out) {
    double Sxx = accD[0], Syy = accD[1], Sxy = accD[2];
    double ns = (double)NS;
    out[0] = (float)(accD[3] / ns);
    out[1] = (float)(accD[4] / ns);
    double sum_xx = 2.0 * Sxx + ns * 5.0;   // diag: 5 exps of 0 each
    double sum_yy = 2.0 * Syy + ns * 5.0;
    out[2] = (float)((sum_xx + sum_yy - 2.0 * Sxy) / (ns * ns));
}

extern "C" void kernel_launch(void* const* d_in, const int* in_sizes, int n_in,
                              void* d_out, int out_size, void* d_ws, size_t ws_size,
                              hipStream_t stream) {
    const float* src  = (const float*)d_in[0];   // (4096, 256)
    const float* tgt  = (const float*)d_in[1];   // (4096, 256)
    const float* sclf = (const float*)d_in[2];   // (4096, 6)
    const float* tclf = (const float*)d_in[3];   // (4096, 6)
    const int*   lab  = (const int*)d_in[4];     // (4096,)
    float* out = (float*)d_out;                  // 3 floats

    char* ws = (char*)d_ws;
    double* accD                 = (double*)ws;                        // 8 doubles
    unsigned long long* rowkey   = (unsigned long long*)(ws + 64);     // 4096 u64
    unsigned long long* colkey   = rowkey + NS;                        // 4096 u64
    float* sq                    = (float*)(ws + 64 + 2 * NS * 8);     // 8192 f32
    float* colsum                = sq + 2 * NS;                        // 256 f32
    float* bwp                   = colsum + D;                         // 1 f32

    k0_init<<<33, 256, 0, stream>>>(accD, rowkey, colkey, colsum);
    k1_sq<<<2 * NS, 64, 0, stream>>>(src, tgt, sq);
    k1b_colsum<<<256, 256, 0, stream>>>(src, tgt, colsum);
    k2_bw<<<1, 256, 0, stream>>>(sq, colsum, bwp);
    k3_pair<<<dim3(64, 64, 3), 256, 0, stream>>>(src, tgt, sq, bwp, accD, rowkey, colkey);
    k4_loss<<<16, 256, 0, stream>>>(sclf, tclf, lab, rowkey, colkey, accD);
    k5_final<<<1, 1, 0, stream>>>(accD, out);
}

// Round 3
// 222.264 us; speedup vs baseline: 1.9331x; 1.9331x over previous
//
#include <hip/hip_runtime.h>
#include <hip/hip_bf16.h>

// ---------------------------------------------------------------------------
// DisNet: clf CE + nearest-neighbor distill + multi-kernel MMD
//   k_conv        : fp32 -> bf16 (RNE) copies of source/target features
//   k0 init       : zero accumulators, min-keys = ~0
//   k1 sq         : per-row squared norms (fp32, exact)
//   k1b colsum    : feature column sums (closed-form sum(l2) for bandwidth)
//   k2 bw         : bandwidth
//   k3 mfma       : pairwise gram via mfma_f32_16x16x32_bf16, fragments
//                   loaded DIRECTLY from global (no LDS tiles, no K-loop
//                   barriers, no bank conflicts); epilogue: 5-kernel RBF sum
//                   + u64-key argmin (z=2)
//   k4 loss       : CE + two distill terms
//   k5 finalize
// ---------------------------------------------------------------------------

#define NS 4096
#define D  256
#define C  6

typedef unsigned long long ull;
typedef unsigned short ushort_t;
typedef __attribute__((ext_vector_type(8))) short short8;
typedef __attribute__((ext_vector_type(8))) unsigned short ushort8v;
typedef __attribute__((ext_vector_type(4))) float floatx4;

#define EXP2F(x) __builtin_amdgcn_exp2f(x)   // v_exp_f32: D = 2^S0

__device__ inline ushort_t f2bf(float f) {
    unsigned u = __float_as_uint(f);
    unsigned r = (u + 0x7FFFu + ((u >> 16) & 1u)) >> 16;
    return (ushort_t)r;
}

// 1024 blocks x 256 threads, 8 elements/thread: convert both matrices
__global__ __launch_bounds__(256) void k_conv(const float* __restrict__ s,
                                              const float* __restrict__ t,
                                              ushort_t* __restrict__ sb,
                                              ushort_t* __restrict__ tb) {
    int gid = blockIdx.x * 256 + threadIdx.x;   // 0..262143
    const float* in = s;
    ushort_t* out = sb;
    int off = gid * 8;
    if (gid >= 131072) { in = t; out = tb; off -= 1048576; }
    float4 v0 = *(const float4*)&in[off];
    float4 v1 = *(const float4*)&in[off + 4];
    ushort8v o;
    o.s0 = f2bf(v0.x); o.s1 = f2bf(v0.y); o.s2 = f2bf(v0.z); o.s3 = f2bf(v0.w);
    o.s4 = f2bf(v1.x); o.s5 = f2bf(v1.y); o.s6 = f2bf(v1.z); o.s7 = f2bf(v1.w);
    *(ushort8v*)&out[off] = o;
}

__global__ __launch_bounds__(256) void k0_init(double* accD, ull* rowkey,
                                               ull* colkey, float* colsum) {
    int i = blockIdx.x * 256 + threadIdx.x;
    if (i < NS) rowkey[i] = ~0ULL;
    else if (i < 2 * NS) colkey[i - NS] = ~0ULL;
    if (i < 8) accD[i] = 0.0;
    if (i < D) colsum[i] = 0.f;
}

__global__ __launch_bounds__(64) void k1_sq(const float* __restrict__ src,
                                            const float* __restrict__ tgt,
                                            float* __restrict__ sq) {
    int r = blockIdx.x;
    const float* row = (r < NS) ? (src + (size_t)r * D) : (tgt + (size_t)(r - NS) * D);
    int l = threadIdx.x;
    float4 v = *(const float4*)&row[l * 4];
    float s = v.x * v.x + v.y * v.y + v.z * v.z + v.w * v.w;
    #pragma unroll
    for (int off = 32; off; off >>= 1) s += __shfl_down(s, off, 64);
    if (l == 0) sq[r] = s;
}

__global__ __launch_bounds__(256) void k1b_colsum(const float* __restrict__ src,
                                                  const float* __restrict__ tgt,
                                                  float* __restrict__ colsum) {
    int c = threadIdx.x;
    int b = blockIdx.x;
    float part = 0.f;
    for (int r = 0; r < 32; r++) {
        int row = b * 32 + r;
        const float* M = (row < NS) ? (src + (size_t)row * D) : (tgt + (size_t)(row - NS) * D);
        part += M[c];
    }
    atomicAdd(&colsum[c], part);
}

__global__ __launch_bounds__(256) void k2_bw(const float* __restrict__ sq,
                                             const float* __restrict__ colsum,
                                             float* __restrict__ bwp) {
    __shared__ float red[256];
    __shared__ float red2[256];
    int t = threadIdx.x;
    float s = 0.f;
    for (int r = t; r < 2 * NS; r += 256) s += sq[r];
    float c = colsum[t];
    red[t] = s;
    red2[t] = c * c;
    __syncthreads();
    for (int off = 128; off; off >>= 1) {
        if (t < off) { red[t] += red[t + off]; red2[t] += red2[t + off]; }
        __syncthreads();
    }
    if (t == 0) {
        double n = 2.0 * NS;
        double sum_l2 = 2.0 * n * (double)red[0] - 2.0 * (double)red2[0];
        double b = sum_l2 / (n * n - n) / 4.0;   // / KERNEL_MUL^(KERNEL_NUM//2)
        bwp[0] = (float)b;
    }
}

// MFMA pairwise kernel. 128x128 tile/block, 4 waves each computing 64x64
// as 4x4 grid of 16x16x32 bf16 MFMAs. Fragments loaded straight from
// global (row-major rows are exactly the A / B^T fragment layout:
// lane holds M[row = base + (lane&15)][k = (lane>>4)*8 .. +7]).
__global__ __launch_bounds__(256) void k3_mfma(const ushort_t* __restrict__ Sb,
                                               const ushort_t* __restrict__ Tb,
                                               const float* __restrict__ sq,
                                               const float* __restrict__ bwp,
                                               double* accD,
                                               ull* rowkey, ull* colkey) {
    int z  = blockIdx.z;
    int ti = blockIdx.y, tj = blockIdx.x;
    if (z != 2 && ti > tj) return;       // symmetric: upper-tri blocks only

    const ushort_t* A = (z == 1) ? Tb : Sb;
    const ushort_t* B = (z == 0) ? Sb : Tb;
    const float* sqA  = (z == 1) ? sq + NS : sq;
    const float* sqB  = (z == 0) ? sq : sq + NS;

    __shared__ float sqa_s[128], sqb_s[128];
    __shared__ ull rmin[128], cmin[128];
    __shared__ float red[256];

    int tid = threadIdx.x;
    int w = tid >> 6, ln = tid & 63;
    int wm = w >> 1, wn = w & 1;
    int quad = ln >> 4, lrow = ln & 15;
    int row0 = ti * 128 + wm * 64;       // global row base of this wave
    int col0 = tj * 128 + wn * 64;       // global col base of this wave
    int lk = quad * 8;

    // stage sq tiles + init LDS min keys (covered by the post-K-loop barrier)
    if (tid < 128) { sqa_s[tid] = sqA[ti * 128 + tid]; rmin[tid] = ~0ULL; }
    else           { sqb_s[tid - 128] = sqB[tj * 128 + tid - 128]; cmin[tid - 128] = ~0ULL; }

    floatx4 acc[4][4] = {};

    #pragma unroll 2
    for (int kc = 0; kc < D; kc += 32) {
        short8 af[4], bf[4];
        #pragma unroll
        for (int rf = 0; rf < 4; rf++)
            af[rf] = *(const short8*)&A[(size_t)(row0 + rf * 16 + lrow) * D + kc + lk];
        #pragma unroll
        for (int cf = 0; cf < 4; cf++)
            bf[cf] = *(const short8*)&B[(size_t)(col0 + cf * 16 + lrow) * D + kc + lk];
        #pragma unroll
        for (int rf = 0; rf < 4; rf++)
            #pragma unroll
            for (int cf = 0; cf < 4; cf++)
                acc[rf][cf] = __builtin_amdgcn_mfma_f32_16x16x32_bf16(
                    af[rf], bf[cf], acc[rf][cf], 0, 0, 0);
    }

    __syncthreads();   // sqa_s/sqb_s/rmin/cmin ready

    // per-lane row/col squared norms (C/D layout: col=lane&15, row=quad*4+reg)
    float sa_r[16], sb_c[4];
    #pragma unroll
    for (int rf = 0; rf < 4; rf++)
        #pragma unroll
        for (int reg = 0; reg < 4; reg++)
            sa_r[rf * 4 + reg] = sqa_s[wm * 64 + rf * 16 + quad * 4 + reg];
    #pragma unroll
    for (int cf = 0; cf < 4; cf++)
        sb_c[cf] = sqb_s[wn * 64 + cf * 16 + lrow];

    float bw = bwp[0];
    float nl[5];
    #pragma unroll
    for (int t = 0; t < 5; t++)
        nl[t] = -1.4426950408889634f / (bw * (float)(1 << t));  // fold log2(e)

    float tsum = 0.f;
    ull ck[4];
    #pragma unroll
    for (int cf = 0; cf < 4; cf++) ck[cf] = ~0ULL;

    #pragma unroll
    for (int rf = 0; rf < 4; rf++) {
        ull rk[4];
        #pragma unroll
        for (int reg = 0; reg < 4; reg++) rk[reg] = ~0ULL;
        #pragma unroll
        for (int cf = 0; cf < 4; cf++) {
            int gj = col0 + cf * 16 + lrow;
            float sbv = sb_c[cf];
            #pragma unroll
            for (int reg = 0; reg < 4; reg++) {
                int gi = row0 + rf * 16 + quad * 4 + reg;
                float l2 = sa_r[rf * 4 + reg] + sbv - 2.0f * acc[rf][cf][reg];
                float kv = EXP2F(l2 * nl[0]) + EXP2F(l2 * nl[1]) +
                           EXP2F(l2 * nl[2]) + EXP2F(l2 * nl[3]) +
                           EXP2F(l2 * nl[4]);
                if (z == 2) {
                    tsum += kv;
                    float d2c = fmaxf(l2, 0.f);
                    ull bits = ((ull)__float_as_uint(d2c)) << 32;
                    ull kr = bits | (unsigned)gj;
                    ull kc_ = bits | (unsigned)gi;
                    if (kr  < rk[reg]) rk[reg] = kr;
                    if (kc_ < ck[cf])  ck[cf]  = kc_;
                } else {
                    if (ti < tj || gi < gj) tsum += kv;   // strict upper only
                }
            }
        }
        if (z == 2) {
            #pragma unroll
            for (int reg = 0; reg < 4; reg++)
                atomicMin(&rmin[wm * 64 + rf * 16 + quad * 4 + reg], rk[reg]);
        }
    }
    if (z == 2) {
        #pragma unroll
        for (int cf = 0; cf < 4; cf++)
            atomicMin(&cmin[wn * 64 + cf * 16 + lrow], ck[cf]);
    }

    // block sum -> one double atomic
    red[tid] = tsum;
    __syncthreads();
    for (int off = 128; off; off >>= 1) {
        if (tid < off) red[tid] += red[tid + off];
        __syncthreads();
    }
    if (tid == 0) atomicAdd(&accD[z], (double)red[0]);

    if (z == 2) {
        if (tid < 128) atomicMin(&rowkey[ti * 128 + tid], rmin[tid]);
        else           atomicMin(&colkey[tj * 128 + tid - 128], cmin[tid - 128]);
    }
}

__global__ __launch_bounds__(256) void k4_loss(const float* __restrict__ sclf,
                                               const float* __restrict__ tclf,
                                               const int* __restrict__ label,
                                               const ull* __restrict__ rowkey,
                                               const ull* __restrict__ colkey,
                                               double* accD) {
    int i = blockIdx.x * 256 + threadIdx.x;   // 0..4095
    float clf = 0.f, dis = 0.f;

    const float* x = sclf + (size_t)i * C;
    float mx = x[0];
    #pragma unroll
    for (int c = 1; c < C; c++) mx = fmaxf(mx, x[c]);
    float sx = 0.f;
    #pragma unroll
    for (int c = 0; c < C; c++) sx += __expf(x[c] - mx);
    float lsex = mx + __logf(sx);
    clf = lsex - x[label[i]];

    {   // teacher = src_clf[i], student = tgt_clf[min_idx[i]]
        int j = (int)(rowkey[i] & 0xffffffffULL);
        const float* y = tclf + (size_t)j * C;
        float my = y[0];
        #pragma unroll
        for (int c = 1; c < C; c++) my = fmaxf(my, y[c]);
        float sy = 0.f;
        #pragma unroll
        for (int c = 0; c < C; c++) sy += __expf(y[c] - my);
        float lsey = my + __logf(sy);
        float dot = 0.f;
        #pragma unroll
        for (int c = 0; c < C; c++) dot += __expf(x[c] - mx) * y[c];
        dot /= sx;
        dis += lsey - dot;
    }
    {   // teacher = src_clf[min_idx_t[i]], student = tgt_clf[i]
        int it = (int)(colkey[i] & 0xffffffffULL);
        const float* xt = sclf + (size_t)it * C;
        float mt = xt[0];
        #pragma unroll
        for (int c = 1; c < C; c++) mt = fmaxf(mt, xt[c]);
        float st = 0.f;
        #pragma unroll
        for (int c = 0; c < C; c++) st += __expf(xt[c] - mt);
        const float* zz = tclf + (size_t)i * C;
        float mz = zz[0];
        #pragma unroll
        for (int c = 1; c < C; c++) mz = fmaxf(mz, zz[c]);
        float sz = 0.f;
        #pragma unroll
        for (int c = 0; c < C; c++) sz += __expf(zz[c] - mz);
        float lsez = mz + __logf(sz);
        float dot2 = 0.f;
        #pragma unroll
        for (int c = 0; c < C; c++) dot2 += __expf(xt[c] - mt) * zz[c];
        dot2 /= st;
        dis += lsez - dot2;
    }

    #pragma unroll
    for (int off = 32; off; off >>= 1) {
        clf += __shfl_down(clf, off, 64);
        dis += __shfl_down(dis, off, 64);
    }
    if ((threadIdx.x & 63) == 0) {
        atomicAdd(&accD[3], (double)clf);
        atomicAdd(&accD[4], (double)dis);
    }
}

__global__ void k5_final(const double* __restrict__ accD, float* __restrict__ out) {
    double Sxx = accD[0], Syy = accD[1], Sxy = accD[2];
    double ns = (double)NS;
    out[0] = (float)(accD[3] / ns);
    out[1] = (float)(accD[4] / ns);
    double sum_xx = 2.0 * Sxx + ns * 5.0;   // diagonal: 5 exps of 0
    double sum_yy = 2.0 * Syy + ns * 5.0;
    out[2] = (float)((sum_xx + sum_yy - 2.0 * Sxy) / (ns * ns));
}

extern "C" void kernel_launch(void* const* d_in, const int* in_sizes, int n_in,
                              void* d_out, int out_size, void* d_ws, size_t ws_size,
                              hipStream_t stream) {
    const float* src  = (const float*)d_in[0];   // (4096, 256)
    const float* tgt  = (const float*)d_in[1];   // (4096, 256)
    const float* sclf = (const float*)d_in[2];   // (4096, 6)
    const float* tclf = (const float*)d_in[3];   // (4096, 6)
    const int*   lab  = (const int*)d_in[4];     // (4096,)
    float* out = (float*)d_out;                  // 3 floats

    char* ws = (char*)d_ws;
    ushort_t* sb  = (ushort_t*)ws;                         // 4096*256 bf16
    ushort_t* tb  = sb + NS * D;                           // 4096*256 bf16
    double* accD  = (double*)(ws + 2 * NS * D * 2);        // 8 doubles (offset 4 MiB)
    ull* rowkey   = (ull*)((char*)accD + 64);              // 4096 u64
    ull* colkey   = rowkey + NS;                           // 4096 u64
    float* sq     = (float*)(colkey + NS);                 // 8192 f32
    float* colsum = sq + 2 * NS;                           // 256 f32
    float* bwp    = colsum + D;                            // 1 f32

    k_conv<<<1024, 256, 0, stream>>>(src, tgt, sb, tb);
    k0_init<<<33, 256, 0, stream>>>(accD, rowkey, colkey, colsum);
    k1_sq<<<2 * NS, 64, 0, stream>>>(src, tgt, sq);
    k1b_colsum<<<256, 256, 0, stream>>>(src, tgt, colsum);
    k2_bw<<<1, 256, 0, stream>>>(sq, colsum, bwp);
    k3_mfma<<<dim3(32, 32, 3), 256, 0, stream>>>(sb, tb, sq, bwp, accD, rowkey, colkey);
    k4_loss<<<16, 256, 0, stream>>>(sclf, tclf, lab, rowkey, colkey, accD);
    k5_final<<<1, 1, 0, stream>>>(accD, out);
}

// Round 4
// 154.247 us; speedup vs baseline: 2.7855x; 1.4410x over previous
//
#include <hip/hip_runtime.h>
#include <hip/hip_bf16.h>

// ---------------------------------------------------------------------------
// DisNet: clf CE + NN distill + multi-kernel MMD. 4 dispatches:
//   kA      : fp32->bf16 convert + row sq-norms + all workspace inits
//   kB      : column sums (bf16 ok: term is ~2e6 of 6.9e10) + bandwidth
//             (last-block-counter pattern)
//   k3_mfma : pairwise gram, m97-style LDS staging (global_load_lds w=16,
//             XOR-swizzled chunks -> conflict-free ds_read_b128), MFMA
//             16x16x32 bf16, RBF epilogue + shuffle-reduced argmin
//   k4      : CE + distill + finalize (last-block-counter)
// ---------------------------------------------------------------------------

#define NS 4096
#define D  256
#define C  6

typedef unsigned long long ull;
typedef unsigned short u16;
typedef __attribute__((ext_vector_type(8))) short short8;
typedef __attribute__((ext_vector_type(4))) unsigned short ushort4v;
typedef __attribute__((ext_vector_type(4))) float floatx4;

#define EXP2F(x) __builtin_amdgcn_exp2f(x)   // v_exp_f32: D = 2^S0

#define GLD_LDS16(g, l)                                                        \
    __builtin_amdgcn_global_load_lds(                                          \
        (const __attribute__((address_space(1))) unsigned int*)(g),            \
        (__attribute__((address_space(3))) unsigned int*)(l), 16, 0, 0)

__device__ inline u16 f2bf(float f) {
    unsigned u = __float_as_uint(f);
    return (u16)((u + 0x7FFFu + ((u >> 16) & 1u)) >> 16);
}
__device__ inline float bf2f(u16 h) {
    return __uint_as_float(((unsigned)h) << 16);
}
__device__ inline ull umin64(ull a, ull b) { return a < b ? a : b; }

// --- kA: 2048 blocks x 256. Wave w -> row b*4+w; lane l -> cols 4l..4l+3 ---
__global__ __launch_bounds__(256) void kA(const float* __restrict__ src,
                                          const float* __restrict__ tgt,
                                          u16* __restrict__ sb, u16* __restrict__ tb,
                                          float* __restrict__ sq,
                                          double* __restrict__ accD,
                                          ull* __restrict__ rowkey,
                                          ull* __restrict__ colkey,
                                          float* __restrict__ colsum,
                                          int* __restrict__ cnts) {
    int b = blockIdx.x, t = threadIdx.x;
    int w = t >> 6, l = t & 63;
    int r = b * 4 + w;                                       // 0..8191
    const float* row = (r < NS) ? src + (size_t)r * D : tgt + (size_t)(r - NS) * D;
    u16* orow        = (r < NS) ? sb + (size_t)r * D : tb + (size_t)(r - NS) * D;
    float4 v = *(const float4*)&row[l * 4];
    ushort4v o;
    o.x = f2bf(v.x); o.y = f2bf(v.y); o.z = f2bf(v.z); o.w = f2bf(v.w);
    *(ushort4v*)&orow[l * 4] = o;
    float s = v.x * v.x + v.y * v.y + v.z * v.z + v.w * v.w;
    #pragma unroll
    for (int off = 32; off; off >>= 1) s += __shfl_down(s, off, 64);
    if (l == 0) sq[r] = s;

    int gid = b * 256 + t;
    if (gid < NS) rowkey[gid] = ~0ULL;
    else if (gid < 2 * NS) colkey[gid - NS] = ~0ULL;
    else if (gid < 2 * NS + D) colsum[gid - 2 * NS] = 0.f;
    else if (gid < 2 * NS + D + 2) cnts[gid - 2 * NS - D] = 0;
    if (gid < 8) accD[gid] = 0.0;
}

// --- kB: 64 blocks x 256: colsum over 8192 rows (bf16 copies), then bw ----
__global__ __launch_bounds__(256) void kB(const u16* __restrict__ sb,
                                          const u16* __restrict__ tb,
                                          const float* __restrict__ sq,
                                          float* __restrict__ colsum,
                                          int* __restrict__ cnts,
                                          float* __restrict__ bwp) {
    int b = blockIdx.x, t = threadIdx.x;
    const u16* M = (b < 32) ? sb + (size_t)b * 128 * D : tb + (size_t)(b - 32) * 128 * D;
    float part = 0.f;
    for (int r = 0; r < 128; r++) part += bf2f(M[(size_t)r * D + t]);
    atomicAdd(&colsum[t], part);
    __threadfence();
    __shared__ int isLast;
    if (t == 0) isLast = (atomicAdd(&cnts[0], 1) == 63);
    __syncthreads();
    if (!isLast) return;

    __shared__ float redA[256], redB[256];
    float ssq = 0.f;
    for (int r = t; r < 2 * NS; r += 256) ssq += sq[r];
    float c = atomicAdd(&colsum[t], 0.0f);                   // atomic read
    redA[t] = ssq; redB[t] = c * c;
    __syncthreads();
    for (int off = 128; off; off >>= 1) {
        if (t < off) { redA[t] += redA[t + off]; redB[t] += redB[t + off]; }
        __syncthreads();
    }
    if (t == 0) {
        double n = 2.0 * NS;
        double sum_l2 = 2.0 * n * (double)redA[0] - 2.0 * (double)redB[0];
        bwp[0] = (float)(sum_l2 / (n * n - n) / 4.0);        // / 2^(5//2)
    }
}

// --- k3: 128x128 tile/block, LDS-staged bf16 MFMA gram + RBF epilogue -----
// bz: 0 = XY (full grid, argmin), 1 = XX upper, 2 = YY upper.
__global__ __launch_bounds__(256) void k3_mfma(const u16* __restrict__ Sb,
                                               const u16* __restrict__ Tb,
                                               const float* __restrict__ sq,
                                               const float* __restrict__ bwp,
                                               double* __restrict__ accD,
                                               ull* __restrict__ rowkey,
                                               ull* __restrict__ colkey) {
    int bz = blockIdx.z;
    int ti = blockIdx.y, tj = blockIdx.x;
    if (bz != 0 && ti > tj) return;

    const u16* Am = (bz == 2) ? Tb : Sb;
    const u16* Bm = (bz == 1) ? Sb : Tb;
    const float* sqA = (bz == 2) ? sq + NS : sq;
    const float* sqB = (bz == 1) ? sq : sq + NS;
    int zacc = (bz == 0) ? 2 : (bz - 1);                     // accD: 0=XX,1=YY,2=XY

    __shared__ __align__(16) u16 Atile[128 * 64];            // 16 KB, 8x16B chunks/row
    __shared__ __align__(16) u16 Btile[128 * 64];            // chunk' = chunk ^ (row&7)
    __shared__ float sqa_s[128], sqb_s[128];
    __shared__ ull rminL[128], cminL[128];
    __shared__ float wsum[4];

    int tid = threadIdx.x;
    int w = tid >> 6, ln = tid & 63;
    int wm = w >> 1, wn = w & 1;
    int quad = ln >> 4, lrow = ln & 15;
    int row0 = ti * 128, col0 = tj * 128;

    if (tid < 128) { sqa_s[tid] = sqA[row0 + tid]; rminL[tid] = ~0ULL; }
    else           { sqb_s[tid - 128] = sqB[col0 + tid - 128]; cminL[tid - 128] = ~0ULL; }

    // staging lane map: localrow = w*32 + i*8 + (ln>>3), LDS chunk' = ln&7,
    // global chunk = (ln&7) ^ (ln>>3)  (since localrow&7 == ln>>3)
    int lr8 = ln >> 3;
    int cg  = (ln & 7) ^ lr8;

    floatx4 acc[4][4] = {};

    for (int kc = 0; kc < D; kc += 64) {
        #pragma unroll
        for (int i = 0; i < 4; i++) {
            int lrb = w * 32 + i * 8;
            GLD_LDS16(Am + (size_t)(row0 + lrb + lr8) * D + kc + cg * 8,
                      &Atile[lrb * 64]);
            GLD_LDS16(Bm + (size_t)(col0 + lrb + lr8) * D + kc + cg * 8,
                      &Btile[lrb * 64]);
        }
        __syncthreads();
        #pragma unroll
        for (int ks = 0; ks < 2; ks++) {
            short8 af[4], bf4[4];
            #pragma unroll
            for (int rf = 0; rf < 4; rf++) {
                int rl = wm * 64 + rf * 16 + lrow;
                int ch = (ks * 4 + quad) ^ (lrow & 7);
                af[rf] = *(const short8*)&Atile[rl * 64 + ch * 8];
            }
            #pragma unroll
            for (int cf = 0; cf < 4; cf++) {
                int rl = wn * 64 + cf * 16 + lrow;
                int ch = (ks * 4 + quad) ^ (lrow & 7);
                bf4[cf] = *(const short8*)&Btile[rl * 64 + ch * 8];
            }
            #pragma unroll
            for (int rf = 0; rf < 4; rf++)
                #pragma unroll
                for (int cf = 0; cf < 4; cf++)
                    acc[rf][cf] = __builtin_amdgcn_mfma_f32_16x16x32_bf16(
                        af[rf], bf4[cf], acc[rf][cf], 0, 0, 0);
        }
        __syncthreads();
    }

    // ---- epilogue: C/D layout col=lane&15, row=quad*4+reg ----
    float sa_r[16], sb_c[4];
    #pragma unroll
    for (int rf = 0; rf < 4; rf++)
        #pragma unroll
        for (int reg = 0; reg < 4; reg++)
            sa_r[rf * 4 + reg] = sqa_s[wm * 64 + rf * 16 + quad * 4 + reg];
    #pragma unroll
    for (int cf = 0; cf < 4; cf++)
        sb_c[cf] = sqb_s[wn * 64 + cf * 16 + lrow];

    float bw = bwp[0];
    float nl[5];
    #pragma unroll
    for (int t = 0; t < 5; t++)
        nl[t] = -1.4426950408889634f / (bw * (float)(1 << t));   // fold log2(e)

    int rbase = row0 + wm * 64, cbase = col0 + wn * 64;
    float tsum = 0.f;

    if (bz == 0) {
        ull ck[4];
        #pragma unroll
        for (int cf = 0; cf < 4; cf++) ck[cf] = ~0ULL;
        #pragma unroll
        for (int rf = 0; rf < 4; rf++) {
            ull rk[4];
            #pragma unroll
            for (int reg = 0; reg < 4; reg++) rk[reg] = ~0ULL;
            #pragma unroll
            for (int cf = 0; cf < 4; cf++) {
                int gj = cbase + cf * 16 + lrow;
                float sbv = sb_c[cf];
                #pragma unroll
                for (int reg = 0; reg < 4; reg++) {
                    int gi = rbase + rf * 16 + quad * 4 + reg;
                    float l2 = sa_r[rf * 4 + reg] + sbv - 2.0f * acc[rf][cf][reg];
                    tsum += EXP2F(l2 * nl[0]) + EXP2F(l2 * nl[1]) +
                            EXP2F(l2 * nl[2]) + EXP2F(l2 * nl[3]) +
                            EXP2F(l2 * nl[4]);
                    ull bits = ((ull)__float_as_uint(fmaxf(l2, 0.f))) << 32;
                    rk[reg] = umin64(rk[reg], bits | (unsigned)gj);
                    ck[cf]  = umin64(ck[cf],  bits | (unsigned)gi);
                }
            }
            // reduce row-mins across the 16 lanes of each quad (xor 1,2,4,8)
            #pragma unroll
            for (int reg = 0; reg < 4; reg++) {
                ull v = rk[reg];
                #pragma unroll
                for (int m = 1; m <= 8; m <<= 1)
                    v = umin64(v, (ull)__shfl_xor((unsigned long long)v, m, 64));
                if (lrow == 0)
                    atomicMin(&rminL[wm * 64 + rf * 16 + quad * 4 + reg], v);
            }
        }
        // reduce col-mins across the 4 quads (xor 16,32)
        #pragma unroll
        for (int cf = 0; cf < 4; cf++) {
            ull v = ck[cf];
            v = umin64(v, (ull)__shfl_xor((unsigned long long)v, 16, 64));
            v = umin64(v, (ull)__shfl_xor((unsigned long long)v, 32, 64));
            if (quad == 0)
                atomicMin(&cminL[wn * 64 + cf * 16 + lrow], v);
        }
    } else {
        #pragma unroll
        for (int rf = 0; rf < 4; rf++)
            #pragma unroll
            for (int cf = 0; cf < 4; cf++) {
                int gj = cbase + cf * 16 + lrow;
                float sbv = sb_c[cf];
                #pragma unroll
                for (int reg = 0; reg < 4; reg++) {
                    int gi = rbase + rf * 16 + quad * 4 + reg;
                    float l2 = sa_r[rf * 4 + reg] + sbv - 2.0f * acc[rf][cf][reg];
                    float kv = EXP2F(l2 * nl[0]) + EXP2F(l2 * nl[1]) +
                               EXP2F(l2 * nl[2]) + EXP2F(l2 * nl[3]) +
                               EXP2F(l2 * nl[4]);
                    if (ti < tj || gi < gj) tsum += kv;   // strict upper only
                }
            }
    }

    #pragma unroll
    for (int off = 32; off; off >>= 1) tsum += __shfl_down(tsum, off, 64);
    if (ln == 0) wsum[w] = tsum;
    __syncthreads();
    if (tid == 0)
        atomicAdd(&accD[zacc], (double)(wsum[0] + wsum[1] + wsum[2] + wsum[3]));
    if (bz == 0) {
        if (tid < 128) atomicMin(&rowkey[row0 + tid], rminL[tid]);
        else           atomicMin(&colkey[col0 + tid - 128], cminL[tid - 128]);
    }
}

// --- k4: 16 blocks x 256: CE + distill; last block finalizes outputs ------
__global__ __launch_bounds__(256) void k4(const float* __restrict__ sclf,
                                          const float* __restrict__ tclf,
                                          const int* __restrict__ label,
                                          const ull* __restrict__ rowkey,
                                          const ull* __restrict__ colkey,
                                          double* __restrict__ accD,
                                          int* __restrict__ cnts,
                                          float* __restrict__ out) {
    int i = blockIdx.x * 256 + threadIdx.x;   // 0..4095
    float clf, dis = 0.f;

    const float* x = sclf + (size_t)i * C;
    float mx = x[0];
    #pragma unroll
    for (int c = 1; c < C; c++) mx = fmaxf(mx, x[c]);
    float sx = 0.f;
    #pragma unroll
    for (int c = 0; c < C; c++) sx += __expf(x[c] - mx);
    clf = mx + __logf(sx) - x[label[i]];

    {   // teacher = src_clf[i], student = tgt_clf[min_idx[i]]
        int j = (int)(rowkey[i] & 0xffffffffULL);
        const float* y = tclf + (size_t)j * C;
        float my = y[0];
        #pragma unroll
        for (int c = 1; c < C; c++) my = fmaxf(my, y[c]);
        float sy = 0.f;
        #pragma unroll
        for (int c = 0; c < C; c++) sy += __expf(y[c] - my);
        float dot = 0.f;
        #pragma unroll
        for (int c = 0; c < C; c++) dot += __expf(x[c] - mx) * y[c];
        dis += my + __logf(sy) - dot / sx;
    }
    {   // teacher = src_clf[min_idx_t[i]], student = tgt_clf[i]
        int it = (int)(colkey[i] & 0xffffffffULL);
        const float* xt = sclf + (size_t)it * C;
        float mt = xt[0];
        #pragma unroll
        for (int c = 1; c < C; c++) mt = fmaxf(mt, xt[c]);
        float st = 0.f;
        #pragma unroll
        for (int c = 0; c < C; c++) st += __expf(xt[c] - mt);
        const float* zz = tclf + (size_t)i * C;
        float mz = zz[0];
        #pragma unroll
        for (int c = 1; c < C; c++) mz = fmaxf(mz, zz[c]);
        float sz = 0.f;
        #pragma unroll
        for (int c = 0; c < C; c++) sz += __expf(zz[c] - mz);
        float dot2 = 0.f;
        #pragma unroll
        for (int c = 0; c < C; c++) dot2 += __expf(xt[c] - mt) * zz[c];
        dis += mz + __logf(sz) - dot2 / st;
    }

    #pragma unroll
    for (int off = 32; off; off >>= 1) {
        clf += __shfl_down(clf, off, 64);
        dis += __shfl_down(dis, off, 64);
    }
    if ((threadIdx.x & 63) == 0) {
        atomicAdd(&accD[3], (double)clf);
        atomicAdd(&accD[4], (double)dis);
    }
    __threadfence();
    __shared__ int isLast;
    if (threadIdx.x == 0) isLast = (atomicAdd(&cnts[1], 1) == (int)gridDim.x - 1);
    __syncthreads();
    if (isLast && threadIdx.x == 0) {
        double Sxx  = atomicAdd(&accD[0], 0.0);
        double Syy  = atomicAdd(&accD[1], 0.0);
        double Sxy  = atomicAdd(&accD[2], 0.0);
        double clfS = atomicAdd(&accD[3], 0.0);
        double disS = atomicAdd(&accD[4], 0.0);
        double ns = (double)NS;
        out[0] = (float)(clfS / ns);
        out[1] = (float)(disS / ns);
        double sum_xx = 2.0 * Sxx + ns * 5.0;   // diagonal: 5 exps of 0
        double sum_yy = 2.0 * Syy + ns * 5.0;
        out[2] = (float)((sum_xx + sum_yy - 2.0 * Sxy) / (ns * ns));
    }
}

extern "C" void kernel_launch(void* const* d_in, const int* in_sizes, int n_in,
                              void* d_out, int out_size, void* d_ws, size_t ws_size,
                              hipStream_t stream) {
    const float* src  = (const float*)d_in[0];   // (4096, 256)
    const float* tgt  = (const float*)d_in[1];   // (4096, 256)
    const float* sclf = (const float*)d_in[2];   // (4096, 6)
    const float* tclf = (const float*)d_in[3];   // (4096, 6)
    const int*   lab  = (const int*)d_in[4];     // (4096,)
    float* out = (float*)d_out;                  // 3 floats

    char* ws = (char*)d_ws;
    u16* sb       = (u16*)ws;                              // 2 MiB
    u16* tb       = sb + (size_t)NS * D;                   // 2 MiB
    double* accD  = (double*)(ws + 2 * (size_t)NS * D * 2);
    ull* rowkey   = (ull*)((char*)accD + 64);
    ull* colkey   = rowkey + NS;
    float* sq     = (float*)(colkey + NS);
    float* colsum = sq + 2 * NS;
    float* bwp    = colsum + D;
    int* cnts     = (int*)(bwp + 1);

    kA<<<2048, 256, 0, stream>>>(src, tgt, sb, tb, sq, accD, rowkey, colkey, colsum, cnts);
    kB<<<64, 256, 0, stream>>>(sb, tb, sq, colsum, cnts, bwp);
    k3_mfma<<<dim3(32, 32, 3), 256, 0, stream>>>(sb, tb, sq, bwp, accD, rowkey, colkey);
    k4<<<16, 256, 0, stream>>>(sclf, tclf, lab, rowkey, colkey, accD, cnts, out);
}